// Round 9
// baseline (21.960 us; speedup 1.0000x reference)
//
#include <hip/hip_runtime.h>
#include <hip/hip_bf16.h>
#include <float.h>

typedef float f32x4 __attribute__((ext_vector_type(4)));
typedef int i32x4 __attribute__((ext_vector_type(4)));

// Kernel 1: argmax over vocab for each (t, b) row.
// x layout: (seq_len, batch, vocab) row-major; row = t*batch + b.
// Intra-wave layout: 16 rows per wave. 8 lanes per row (lane>>3 = group g,
// lane&7 = sub-lane); group g scans rows row0+g AND row0+8+g with two
// independent compare chains (2x memory-level parallelism per lane).
// Reduce: 3 __shfl_xor steps, both rows interleaved.
// Rows with t >= lengths[b] are skipped (never consumed downstream).
// Output ml stored TRANSPOSED: ml[b*seq_len + t].
__global__ __launch_bounds__(256) void ctc_argmax_kernel(
    const float* __restrict__ x,
    int* __restrict__ ml,
    const int* __restrict__ lengths,
    int seq_len, int batch, int vocab) {
    const int nrows = seq_len * batch;

    const int lane = threadIdx.x & 63;
    const int wave = blockIdx.x * (blockDim.x >> 6) + (threadIdx.x >> 6);
    const int row0 = wave * 16;
    if (row0 >= nrows) return;

    const int g = lane >> 3;    // group 0..7
    const int sl = lane & 7;    // sub-lane within group
    const int rowA = row0 + g;
    const int rowB = row0 + 8 + g;

    bool actA = false, actB = false;
    int tA = 0, bA = 0, tB = 0, bB = 0;
    if (rowA < nrows) {
        tA = rowA / batch; bA = rowA - tA * batch;
        actA = (tA < lengths[bA]);
    }
    if (rowB < nrows) {
        tB = rowB / batch; bB = rowB - tB * batch;
        actB = (tB < lengths[bB]);
    }
    if (!__any(actA || actB)) return;

    float bestA = -FLT_MAX, bestB = -FLT_MAX;
    int idxA = vocab, idxB = vocab;

    const int vmain = vocab & ~31;   // multiple of 32 floats (8 lanes x 4)
    const float* pA = x + (size_t)rowA * vocab + sl * 4;
    const float* pB = x + (size_t)rowB * vocab + sl * 4;

    for (int base = 0; base < vmain; base += 32) {
        f32x4 vA, vB;
        if (actA) vA = *reinterpret_cast<const f32x4*>(pA + base);
        if (actB) vB = *reinterpret_cast<const f32x4*>(pB + base);
        const int i0 = base + sl * 4;
        if (actA) {
#pragma unroll
            for (int j = 0; j < 4; ++j) {
                if (vA[j] > bestA) { bestA = vA[j]; idxA = i0 + j; }
            }
        }
        if (actB) {
#pragma unroll
            for (int j = 0; j < 4; ++j) {
                if (vB[j] > bestB) { bestB = vB[j]; idxB = i0 + j; }
            }
        }
    }
    // Scalar tail (vocab % 32 != 0); tail indices exceed main indices.
    for (int i = vmain + sl; i < vocab; i += 8) {
        if (actA) {
            float v = x[(size_t)rowA * vocab + i];
            if (v > bestA) { bestA = v; idxA = i; }
        }
        if (actB) {
            float v = x[(size_t)rowB * vocab + i];
            if (v > bestB) { bestB = v; idxB = i; }
        }
    }

    // 3-step xor reduce within each 8-lane group, both rows interleaved.
    // Larger value wins; on tie, lower index wins (first occurrence).
#pragma unroll
    for (int m = 1; m <= 4; m <<= 1) {
        float ovA = __shfl_xor(bestA, m, 64);
        int oiA = __shfl_xor(idxA, m, 64);
        float ovB = __shfl_xor(bestB, m, 64);
        int oiB = __shfl_xor(idxB, m, 64);
        if (ovA > bestA || (ovA == bestA && oiA < idxA)) { bestA = ovA; idxA = oiA; }
        if (ovB > bestB || (ovB == bestB && oiB < idxB)) { bestB = ovB; idxB = oiB; }
    }

    if (sl == 0) {
        if (actA) ml[(size_t)bA * seq_len + tA] = idxA;
        if (actB) ml[(size_t)bB * seq_len + tB] = idxB;
    }
}

// Kernel 2: per-batch removal of blanks and consecutive duplicates + left-pack.
// One block (512 threads) per batch element. Fills its own tokens row with -1
// (vectorized) before scattering. ml entries at t >= lengths[b] may be
// garbage; keep=false there, and prev at any kept t reads t-1 < len.
__global__ __launch_bounds__(512) void ctc_compact_kernel(
    const int* __restrict__ ml,
    const int* __restrict__ lengths,
    const int* __restrict__ blank_ptr,
    int* __restrict__ tokens,
    int* __restrict__ out_lengths,
    int seq_len, int batch) {
    constexpr int MAXPER = 16;
    const int b = blockIdx.x;
    if (b >= batch) return;
    const int blank = *blank_ptr;
    const int len = lengths[b];
    const int* row = ml + (size_t)b * seq_len;
    int* out = tokens + (size_t)b * seq_len;

    const int tid = threadIdx.x;
    const int nthr = blockDim.x;

    // -1 fill of this block's output row, vectorized.
    const int nv4 = seq_len >> 2;
    i32x4* out4 = reinterpret_cast<i32x4*>(out);
    for (int i = tid; i < nv4; i += nthr) out4[i] = i32x4{-1, -1, -1, -1};
    for (int i = (nv4 << 2) + tid; i < seq_len; i += nthr) out[i] = -1;
    __syncthreads();

    const int per = (seq_len + nthr - 1) / nthr;  // 4 for 2048/512

    const int t0 = tid * per;
    int vals[MAXPER];
    unsigned keep_mask = 0;
    int cnt = 0;

    if (per == 4 && t0 + 4 <= seq_len && (seq_len & 3) == 0) {
        // Fast path: one aligned int4 load for this thread's 4 timesteps.
        i32x4 v4 = *reinterpret_cast<const i32x4*>(row + t0);
        int prev = (t0 == 0) ? -1 : row[t0 - 1];
#pragma unroll
        for (int j = 0; j < 4; ++j) {
            const int t = t0 + j;
            const int v = v4[j];
            const bool k = (t < len) && (v != blank) &&
                           (prev == blank || v != prev);
            vals[j] = v;
            if (k) { keep_mask |= (1u << j); ++cnt; }
            prev = v;
        }
    } else {
        int prev = (t0 == 0) ? -1 : ((t0 - 1 < seq_len) ? row[t0 - 1] : -1);
        for (int j = 0; j < per && j < MAXPER; ++j) {
            const int t = t0 + j;
            if (t >= seq_len) break;
            const int v = row[t];
            const bool k = (t < len) && (v != blank) &&
                           (prev == blank || v != prev);
            vals[j] = v;
            if (k) { keep_mask |= (1u << j); ++cnt; }
            prev = v;
        }
    }

    // Block-wide exclusive prefix sum of cnt (thread order).
    __shared__ int warp_sums[8];
    const int lane = tid & 63;
    const int wid = tid >> 6;
    int incl = cnt;
#pragma unroll
    for (int off = 1; off < 64; off <<= 1) {
        int n = __shfl_up(incl, off, 64);
        if (lane >= off) incl += n;
    }
    if (lane == 63) warp_sums[wid] = incl;
    __syncthreads();

    int wbase = 0;
    for (int w = 0; w < wid; ++w) wbase += warp_sums[w];
    int pos = wbase + incl - cnt;  // exclusive prefix for this thread

    for (int j = 0; j < per && j < MAXPER; ++j) {
        if (keep_mask & (1u << j)) out[pos++] = vals[j];
    }

    if (tid == 0) {
        int total = 0;
        const int nwaves = nthr >> 6;
        for (int w = 0; w < nwaves; ++w) total += warp_sums[w];
        out_lengths[b] = total;
    }
}

extern "C" void kernel_launch(void* const* d_in, const int* in_sizes, int n_in,
                              void* d_out, int out_size, void* d_ws, size_t ws_size,
                              hipStream_t stream) {
    const float* x = (const float*)d_in[0];
    const int* lengths = (const int*)d_in[1];
    const int* blank_ptr = (const int*)d_in[2];

    const int batch = in_sizes[1];
    const int seq_len = (out_size - batch) / batch;      // tokens is (batch, seq_len)
    const int vocab = in_sizes[0] / (seq_len * batch);

    int* tokens = (int*)d_out;                                  // (batch, seq_len)
    int* out_lengths = (int*)d_out + (size_t)batch * seq_len;   // (batch,)
    int* ml = (int*)d_ws;                                       // (batch, seq_len)

    // Kernel 1: 16 rows per wave (8 lanes/row, 2 rows/group), 4 waves/block.
    const int nrows = seq_len * batch;
    const int ntasks = (nrows + 15) / 16;
    const int waves_per_block = 4;
    const int blocks1 = (ntasks + waves_per_block - 1) / waves_per_block;
    ctc_argmax_kernel<<<blocks1, waves_per_block * 64, 0, stream>>>(
        x, ml, lengths, seq_len, batch, vocab);

    // Kernel 2: one block per batch element, 512 threads.
    ctc_compact_kernel<<<batch, 512, 0, stream>>>(
        ml, lengths, blank_ptr, tokens, out_lengths, seq_len, batch);
}

// Round 10
// 21.254 us; speedup vs baseline: 1.0332x; 1.0332x over previous
//
#include <hip/hip_runtime.h>
#include <hip/hip_bf16.h>
#include <float.h>

typedef float f32x4 __attribute__((ext_vector_type(4)));
typedef int i32x4 __attribute__((ext_vector_type(4)));

// Kernel 1: argmax over vocab for each (t, b) row.
// x layout: (seq_len, batch, vocab) row-major; row = t*batch + b.
// Intra-wave layout: 8 rows per wave, 8 lanes per row (lane>>3 = row group,
// lane&7 = sub-lane). Each lane scans vocab/8 elements of its row; the
// argmax reduce is 3 __shfl_xor steps for all 8 rows in parallel.
// Rows with t >= lengths[b] are skipped (never consumed downstream).
// Output ml stored TRANSPOSED: ml[b*seq_len + t].
__global__ __launch_bounds__(256) void ctc_argmax_kernel(
    const float* __restrict__ x,
    int* __restrict__ ml,
    const int* __restrict__ lengths,
    int seq_len, int batch, int vocab) {
    const int nrows = seq_len * batch;

    const int lane = threadIdx.x & 63;
    const int wave = blockIdx.x * (blockDim.x >> 6) + (threadIdx.x >> 6);
    const int row0 = wave * 8;
    if (row0 >= nrows) return;

    const int g = lane >> 3;    // row group 0..7
    const int sl = lane & 7;    // sub-lane within group
    const int row = row0 + g;

    bool act = false;
    int t = 0, b = 0;
    if (row < nrows) {
        t = row / batch;
        b = row - t * batch;
        act = (t < lengths[b]);   // uniform within the 8-lane group
    }
    if (!__any(act)) return;

    float best = -FLT_MAX;
    int bidx = vocab;

    if (act) {
        const int vmain = vocab & ~31;   // multiple of 32 floats (8 lanes x 4)
        const float* p = x + (size_t)row * vocab + sl * 4;
        for (int base = 0; base < vmain; base += 32) {
            f32x4 v = *reinterpret_cast<const f32x4*>(p + base);
            const int i0 = base + sl * 4;
#pragma unroll
            for (int j = 0; j < 4; ++j) {
                if (v[j] > best) { best = v[j]; bidx = i0 + j; }
            }
        }
        // Scalar tail (vocab % 32 != 0); tail indices exceed main indices,
        // strict '>' keeps the earlier occurrence; ties resolved in reduce.
        for (int i = vmain + sl; i < vocab; i += 8) {
            float v = x[(size_t)row * vocab + i];
            if (v > best) { best = v; bidx = i; }
        }
    }

    // 3-step xor reduce within each 8-lane group (all 8 rows in parallel).
    // Larger value wins; on tie, lower index wins (first occurrence).
#pragma unroll
    for (int m = 1; m <= 4; m <<= 1) {
        float ov = __shfl_xor(best, m, 64);
        int oi = __shfl_xor(bidx, m, 64);
        if (ov > best || (ov == best && oi < bidx)) { best = ov; bidx = oi; }
    }

    if (act && sl == 0) {
        ml[(size_t)b * seq_len + t] = bidx;
    }
}

// Kernel 2: per-batch removal of blanks and consecutive duplicates + left-pack.
// One block (512 threads) per batch element. Fills its own tokens row with -1
// (vectorized) before scattering. ml entries at t >= lengths[b] may be
// garbage; keep=false there, and prev at any kept t reads t-1 < len.
__global__ __launch_bounds__(512) void ctc_compact_kernel(
    const int* __restrict__ ml,
    const int* __restrict__ lengths,
    const int* __restrict__ blank_ptr,
    int* __restrict__ tokens,
    int* __restrict__ out_lengths,
    int seq_len, int batch) {
    constexpr int MAXPER = 16;
    const int b = blockIdx.x;
    if (b >= batch) return;
    const int blank = *blank_ptr;
    const int len = lengths[b];
    const int* row = ml + (size_t)b * seq_len;
    int* out = tokens + (size_t)b * seq_len;

    const int tid = threadIdx.x;
    const int nthr = blockDim.x;

    // -1 fill of this block's output row, vectorized.
    const int nv4 = seq_len >> 2;
    i32x4* out4 = reinterpret_cast<i32x4*>(out);
    for (int i = tid; i < nv4; i += nthr) out4[i] = i32x4{-1, -1, -1, -1};
    for (int i = (nv4 << 2) + tid; i < seq_len; i += nthr) out[i] = -1;
    __syncthreads();

    const int per = (seq_len + nthr - 1) / nthr;  // 4 for 2048/512

    const int t0 = tid * per;
    int vals[MAXPER];
    unsigned keep_mask = 0;
    int cnt = 0;

    if (per == 4 && t0 + 4 <= seq_len && (seq_len & 3) == 0) {
        // Fast path: one aligned int4 load for this thread's 4 timesteps.
        i32x4 v4 = *reinterpret_cast<const i32x4*>(row + t0);
        int prev = (t0 == 0) ? -1 : row[t0 - 1];
#pragma unroll
        for (int j = 0; j < 4; ++j) {
            const int t = t0 + j;
            const int v = v4[j];
            const bool k = (t < len) && (v != blank) &&
                           (prev == blank || v != prev);
            vals[j] = v;
            if (k) { keep_mask |= (1u << j); ++cnt; }
            prev = v;
        }
    } else {
        int prev = (t0 == 0) ? -1 : ((t0 - 1 < seq_len) ? row[t0 - 1] : -1);
        for (int j = 0; j < per && j < MAXPER; ++j) {
            const int t = t0 + j;
            if (t >= seq_len) break;
            const int v = row[t];
            const bool k = (t < len) && (v != blank) &&
                           (prev == blank || v != prev);
            vals[j] = v;
            if (k) { keep_mask |= (1u << j); ++cnt; }
            prev = v;
        }
    }

    // Block-wide exclusive prefix sum of cnt (thread order).
    __shared__ int warp_sums[8];
    const int lane = tid & 63;
    const int wid = tid >> 6;
    int incl = cnt;
#pragma unroll
    for (int off = 1; off < 64; off <<= 1) {
        int n = __shfl_up(incl, off, 64);
        if (lane >= off) incl += n;
    }
    if (lane == 63) warp_sums[wid] = incl;
    __syncthreads();

    int wbase = 0;
    for (int w = 0; w < wid; ++w) wbase += warp_sums[w];
    int pos = wbase + incl - cnt;  // exclusive prefix for this thread

    for (int j = 0; j < per && j < MAXPER; ++j) {
        if (keep_mask & (1u << j)) out[pos++] = vals[j];
    }

    if (tid == 0) {
        int total = 0;
        const int nwaves = nthr >> 6;
        for (int w = 0; w < nwaves; ++w) total += warp_sums[w];
        out_lengths[b] = total;
    }
}

extern "C" void kernel_launch(void* const* d_in, const int* in_sizes, int n_in,
                              void* d_out, int out_size, void* d_ws, size_t ws_size,
                              hipStream_t stream) {
    const float* x = (const float*)d_in[0];
    const int* lengths = (const int*)d_in[1];
    const int* blank_ptr = (const int*)d_in[2];

    const int batch = in_sizes[1];
    const int seq_len = (out_size - batch) / batch;      // tokens is (batch, seq_len)
    const int vocab = in_sizes[0] / (seq_len * batch);

    int* tokens = (int*)d_out;                                  // (batch, seq_len)
    int* out_lengths = (int*)d_out + (size_t)batch * seq_len;   // (batch,)
    int* ml = (int*)d_ws;                                       // (batch, seq_len)

    // Kernel 1: 8 rows per wave (8 lanes each), 4 waves per 256-thread block.
    const int nrows = seq_len * batch;
    const int ntasks = (nrows + 7) / 8;
    const int waves_per_block = 4;
    const int blocks1 = (ntasks + waves_per_block - 1) / waves_per_block;
    ctc_argmax_kernel<<<blocks1, waves_per_block * 64, 0, stream>>>(
        x, ml, lengths, seq_len, batch, vocab);

    // Kernel 2: one block per batch element, 512 threads.
    ctc_compact_kernel<<<batch, 512, 0, stream>>>(
        ml, lengths, blank_ptr, tokens, out_lengths, seq_len, batch);
}

// Round 11
// 21.251 us; speedup vs baseline: 1.0334x; 1.0001x over previous
//
#include <hip/hip_runtime.h>
#include <hip/hip_bf16.h>
#include <float.h>

typedef float f32x4 __attribute__((ext_vector_type(4)));
typedef int i32x4 __attribute__((ext_vector_type(4)));

// Kernel 1: argmax over vocab for each (t, b) row.
// x layout: (seq_len, batch, vocab) row-major; row = t*batch + b.
// Intra-wave layout: 8 rows per wave, 8 lanes per row (lane>>3 = row group,
// lane&7 = sub-lane). Each lane scans vocab/8 elements of its row; the
// argmax reduce is 3 __shfl_xor steps for all 8 rows in parallel.
// Rows with t >= lengths[b] are skipped (never consumed downstream).
// Output ml stored TRANSPOSED: ml[b*seq_len + t]. Also fills tokens with -1.
// 512-thread blocks (8 waves) halve block count vs 256-thread config.
__global__ __launch_bounds__(512) void ctc_argmax_kernel(
    const float* __restrict__ x,
    int* __restrict__ ml,
    const int* __restrict__ lengths,
    int* __restrict__ tokens,
    int seq_len, int batch, int vocab) {
    const int nrows = seq_len * batch;

    // -1 fill of tokens (batch*seq_len ints), grid-strided (effectively free).
    const int gtid = blockIdx.x * blockDim.x + threadIdx.x;
    const int gstride = gridDim.x * blockDim.x;
    for (int i = gtid; i < nrows; i += gstride) tokens[i] = -1;

    const int lane = threadIdx.x & 63;
    const int wave = blockIdx.x * (blockDim.x >> 6) + (threadIdx.x >> 6);
    const int row0 = wave * 8;
    if (row0 >= nrows) return;

    const int g = lane >> 3;    // row group 0..7
    const int sl = lane & 7;    // sub-lane within group
    const int row = row0 + g;

    bool act = false;
    int t = 0, b = 0;
    if (row < nrows) {
        t = row / batch;
        b = row - t * batch;
        act = (t < lengths[b]);   // uniform within the 8-lane group
    }
    if (!__any(act)) return;

    float best = -FLT_MAX;
    int bidx = vocab;

    if (act) {
        const int vmain = vocab & ~31;   // multiple of 32 floats (8 lanes x 4)
        const float* p = x + (size_t)row * vocab + sl * 4;
        for (int base = 0; base < vmain; base += 32) {
            f32x4 v = *reinterpret_cast<const f32x4*>(p + base);
            const int i0 = base + sl * 4;
#pragma unroll
            for (int j = 0; j < 4; ++j) {
                if (v[j] > best) { best = v[j]; bidx = i0 + j; }
            }
        }
        // Scalar tail (vocab % 32 != 0); tail indices exceed main indices,
        // strict '>' keeps the earlier occurrence; ties resolved in reduce.
        for (int i = vmain + sl; i < vocab; i += 8) {
            float v = x[(size_t)row * vocab + i];
            if (v > best) { best = v; bidx = i; }
        }
    }

    // 3-step xor reduce within each 8-lane group (all 8 rows in parallel).
    // Larger value wins; on tie, lower index wins (first occurrence).
#pragma unroll
    for (int m = 1; m <= 4; m <<= 1) {
        float ov = __shfl_xor(best, m, 64);
        int oi = __shfl_xor(bidx, m, 64);
        if (ov > best || (ov == best && oi < bidx)) { best = ov; bidx = oi; }
    }

    if (act && sl == 0) {
        ml[(size_t)b * seq_len + t] = bidx;
    }
}

// Kernel 2: per-batch removal of blanks and consecutive duplicates + left-pack.
// One block (512 threads) per batch element. tokens[] pre-filled with -1 by
// kernel 1. ml entries at t >= lengths[b] may be garbage; keep=false there
// and such vals are never scattered, so we skip loading chunks entirely
// beyond len (halves the average read).
__global__ __launch_bounds__(512) void ctc_compact_kernel(
    const int* __restrict__ ml,
    const int* __restrict__ lengths,
    const int* __restrict__ blank_ptr,
    int* __restrict__ tokens,
    int* __restrict__ out_lengths,
    int seq_len, int batch) {
    constexpr int MAXPER = 16;
    const int b = blockIdx.x;
    if (b >= batch) return;
    const int blank = *blank_ptr;
    const int len = lengths[b];
    const int* row = ml + (size_t)b * seq_len;
    int* out = tokens + (size_t)b * seq_len;

    const int tid = threadIdx.x;
    const int nthr = blockDim.x;
    const int per = (seq_len + nthr - 1) / nthr;  // 4 for 2048/512

    const int t0 = tid * per;
    int vals[MAXPER];
    unsigned keep_mask = 0;
    int cnt = 0;

    if (per == 4 && t0 + 4 <= seq_len && (seq_len & 3) == 0) {
        if (t0 < len) {
            // One aligned int4 load for this thread's 4 timesteps.
            i32x4 v4 = *reinterpret_cast<const i32x4*>(row + t0);
            int prev = (t0 == 0) ? -1 : row[t0 - 1];
#pragma unroll
            for (int j = 0; j < 4; ++j) {
                const int t = t0 + j;
                const int v = v4[j];
                const bool k = (t < len) && (v != blank) &&
                               (prev == blank || v != prev);
                vals[j] = v;
                if (k) { keep_mask |= (1u << j); ++cnt; }
                prev = v;
            }
        }
        // else: entire chunk beyond len -> keep nothing, read nothing.
    } else {
        int prev = (t0 == 0) ? -1 : ((t0 - 1 < seq_len) ? row[t0 - 1] : -1);
        for (int j = 0; j < per && j < MAXPER; ++j) {
            const int t = t0 + j;
            if (t >= seq_len || t >= len) break;
            const int v = row[t];
            const bool k = (v != blank) && (prev == blank || v != prev);
            vals[j] = v;
            if (k) { keep_mask |= (1u << j); ++cnt; }
            prev = v;
        }
    }

    // Block-wide exclusive prefix sum of cnt (thread order).
    __shared__ int warp_sums[8];
    const int lane = tid & 63;
    const int wid = tid >> 6;
    int incl = cnt;
#pragma unroll
    for (int off = 1; off < 64; off <<= 1) {
        int n = __shfl_up(incl, off, 64);
        if (lane >= off) incl += n;
    }
    if (lane == 63) warp_sums[wid] = incl;
    __syncthreads();

    int wbase = 0;
    for (int w = 0; w < wid; ++w) wbase += warp_sums[w];
    int pos = wbase + incl - cnt;  // exclusive prefix for this thread

    for (int j = 0; j < per && j < MAXPER; ++j) {
        if (keep_mask & (1u << j)) out[pos++] = vals[j];
    }

    if (tid == 0) {
        int total = 0;
        const int nwaves = nthr >> 6;
        for (int w = 0; w < nwaves; ++w) total += warp_sums[w];
        out_lengths[b] = total;
    }
}

extern "C" void kernel_launch(void* const* d_in, const int* in_sizes, int n_in,
                              void* d_out, int out_size, void* d_ws, size_t ws_size,
                              hipStream_t stream) {
    const float* x = (const float*)d_in[0];
    const int* lengths = (const int*)d_in[1];
    const int* blank_ptr = (const int*)d_in[2];

    const int batch = in_sizes[1];
    const int seq_len = (out_size - batch) / batch;      // tokens is (batch, seq_len)
    const int vocab = in_sizes[0] / (seq_len * batch);

    int* tokens = (int*)d_out;                                  // (batch, seq_len)
    int* out_lengths = (int*)d_out + (size_t)batch * seq_len;   // (batch,)
    int* ml = (int*)d_ws;                                       // (batch, seq_len)

    // Kernel 1: 8 rows per wave (8 lanes each), 8 waves per 512-thread block.
    const int nrows = seq_len * batch;
    const int ntasks = (nrows + 7) / 8;
    const int waves_per_block = 8;
    const int blocks1 = (ntasks + waves_per_block - 1) / waves_per_block;
    ctc_argmax_kernel<<<blocks1, waves_per_block * 64, 0, stream>>>(
        x, ml, lengths, tokens, seq_len, batch, vocab);

    // Kernel 2: one block per batch element, 512 threads.
    ctc_compact_kernel<<<batch, 512, 0, stream>>>(
        ml, lengths, blank_ptr, tokens, out_lengths, seq_len, batch);
}

// Round 12
// 20.270 us; speedup vs baseline: 1.0834x; 1.0484x over previous
//
#include <hip/hip_runtime.h>
#include <hip/hip_bf16.h>
#include <float.h>

typedef float f32x4 __attribute__((ext_vector_type(4)));
typedef int i32x4 __attribute__((ext_vector_type(4)));

// Kernel 1 (dense): argmax over vocab for the ACTIVE (t,b) rows only.
// x layout: (seq_len, batch, vocab) row-major; row = t*batch + b.
// Active row k (b-major order: batch b contributes t=0..len[b]-1) is found
// via a per-wave prefix sum of lengths (batch<=64) + shuffle binary search.
// Intra-wave: 8 tasks per wave, 8 lanes per task (lane>>3 = group, lane&7 =
// sub-lane); 3-step __shfl_xor reduce for all 8 tasks in parallel.
// Output ml stored TRANSPOSED: ml[b*seq_len + t]. Also fills tokens with -1.
__global__ __launch_bounds__(256) void ctc_argmax_dense(
    const float* __restrict__ x,
    int* __restrict__ ml,
    const int* __restrict__ lengths,
    int* __restrict__ tokens,
    int seq_len, int batch, int vocab) {
    const int nrows = seq_len * batch;

    // -1 fill of tokens (batch*seq_len ints), grid-strided (measured free).
    const int gtid = blockIdx.x * blockDim.x + threadIdx.x;
    const int gstride = gridDim.x * blockDim.x;
    for (int i = gtid; i < nrows; i += gstride) tokens[i] = -1;

    const int lane = threadIdx.x & 63;
    const int wave = blockIdx.x * (blockDim.x >> 6) + (threadIdx.x >> 6);

    // Inclusive prefix sum of lengths across lanes (batch <= 64).
    int myLen = (lane < batch) ? lengths[lane] : 0;
    int incl = myLen;
#pragma unroll
    for (int off = 1; off < 64; off <<= 1) {
        int n = __shfl_up(incl, off, 64);
        if (lane >= off) incl += n;
    }
    const int total = __shfl(incl, 63, 64);  // sum of lengths

    const int k0 = wave * 8;
    if (k0 >= total) return;  // inactive wave: retire after cheap prologue

    const int g = lane >> 3;    // task group 0..7
    const int sl = lane & 7;    // sub-lane within group
    const int k = k0 + g;       // this group's dense task id
    const bool act = (k < total);

    // Lower-bound search: b = #lanes with incl <= k (skips len==0 correctly).
    int pos = 0;
#pragma unroll
    for (int step = 32; step >= 1; step >>= 1) {
        const int probe = pos + step - 1;
        const int v = __shfl(incl, probe, 64);
        if (v <= k) pos += step;
    }
    const int b = pos;  // uniform within group (valid when act)
    const int baseRaw = __shfl(incl, (b == 0) ? 0 : b - 1, 64);
    const int base = (b == 0) ? 0 : baseRaw;
    const int t = k - base;     // 0 <= t < len[b] when act

    float best = -FLT_MAX;
    int bidx = vocab;

    if (act) {
        const int vmain = vocab & ~31;   // multiple of 32 floats (8 lanes x 4)
        const float* p = x + ((size_t)t * batch + b) * vocab + sl * 4;
        for (int base2 = 0; base2 < vmain; base2 += 32) {
            f32x4 v = *reinterpret_cast<const f32x4*>(p + base2);
            const int i0 = base2 + sl * 4;
#pragma unroll
            for (int j = 0; j < 4; ++j) {
                if (v[j] > best) { best = v[j]; bidx = i0 + j; }
            }
        }
        // Scalar tail (vocab % 32 != 0); tail indices exceed main indices,
        // strict '>' keeps the earlier occurrence; ties resolved in reduce.
        for (int i = vmain + sl; i < vocab; i += 8) {
            float v = x[((size_t)t * batch + b) * vocab + i];
            if (v > best) { best = v; bidx = i; }
        }
    }

    // 3-step xor reduce within each 8-lane group (all 8 tasks in parallel).
    // Larger value wins; on tie, lower index wins (first occurrence).
#pragma unroll
    for (int m = 1; m <= 4; m <<= 1) {
        float ov = __shfl_xor(best, m, 64);
        int oi = __shfl_xor(bidx, m, 64);
        if (ov > best || (ov == best && oi < bidx)) { best = ov; bidx = oi; }
    }

    if (act && sl == 0) {
        ml[(size_t)b * seq_len + t] = bidx;
    }
}

// Fallback (batch > 64): R8's interleaved-row argmax.
__global__ __launch_bounds__(256) void ctc_argmax_kernel(
    const float* __restrict__ x,
    int* __restrict__ ml,
    const int* __restrict__ lengths,
    int* __restrict__ tokens,
    int seq_len, int batch, int vocab) {
    const int nrows = seq_len * batch;

    const int gtid = blockIdx.x * blockDim.x + threadIdx.x;
    const int gstride = gridDim.x * blockDim.x;
    for (int i = gtid; i < nrows; i += gstride) tokens[i] = -1;

    const int lane = threadIdx.x & 63;
    const int wave = blockIdx.x * (blockDim.x >> 6) + (threadIdx.x >> 6);
    const int row0 = wave * 8;
    if (row0 >= nrows) return;

    const int g = lane >> 3;
    const int sl = lane & 7;
    const int row = row0 + g;

    bool act = false;
    int t = 0, b = 0;
    if (row < nrows) {
        t = row / batch;
        b = row - t * batch;
        act = (t < lengths[b]);
    }
    if (!__any(act)) return;

    float best = -FLT_MAX;
    int bidx = vocab;

    if (act) {
        const int vmain = vocab & ~31;
        const float* p = x + (size_t)row * vocab + sl * 4;
        for (int base = 0; base < vmain; base += 32) {
            f32x4 v = *reinterpret_cast<const f32x4*>(p + base);
            const int i0 = base + sl * 4;
#pragma unroll
            for (int j = 0; j < 4; ++j) {
                if (v[j] > best) { best = v[j]; bidx = i0 + j; }
            }
        }
        for (int i = vmain + sl; i < vocab; i += 8) {
            float v = x[(size_t)row * vocab + i];
            if (v > best) { best = v; bidx = i; }
        }
    }

#pragma unroll
    for (int m = 1; m <= 4; m <<= 1) {
        float ov = __shfl_xor(best, m, 64);
        int oi = __shfl_xor(bidx, m, 64);
        if (ov > best || (ov == best && oi < bidx)) { best = ov; bidx = oi; }
    }

    if (act && sl == 0) {
        ml[(size_t)b * seq_len + t] = bidx;
    }
}

// Kernel 2: per-batch removal of blanks and consecutive duplicates + left-pack.
// One block (512 threads) per batch element. tokens[] pre-filled with -1 by
// kernel 1. ml entries at t >= lengths[b] may be garbage; keep=false there,
// and prev at any kept t reads t-1 < len, so garbage never influences output.
__global__ __launch_bounds__(512) void ctc_compact_kernel(
    const int* __restrict__ ml,
    const int* __restrict__ lengths,
    const int* __restrict__ blank_ptr,
    int* __restrict__ tokens,
    int* __restrict__ out_lengths,
    int seq_len, int batch) {
    constexpr int MAXPER = 16;
    const int b = blockIdx.x;
    if (b >= batch) return;
    const int blank = *blank_ptr;
    const int len = lengths[b];
    const int* row = ml + (size_t)b * seq_len;
    int* out = tokens + (size_t)b * seq_len;

    const int tid = threadIdx.x;
    const int nthr = blockDim.x;
    const int per = (seq_len + nthr - 1) / nthr;  // 4 for 2048/512

    const int t0 = tid * per;
    int vals[MAXPER];
    unsigned keep_mask = 0;
    int cnt = 0;

    if (per == 4 && t0 + 4 <= seq_len && (seq_len & 3) == 0) {
        // Fast path: one aligned int4 load for this thread's 4 timesteps.
        i32x4 v4 = *reinterpret_cast<const i32x4*>(row + t0);
        int prev = (t0 == 0) ? -1 : row[t0 - 1];
#pragma unroll
        for (int j = 0; j < 4; ++j) {
            const int t = t0 + j;
            const int v = v4[j];
            const bool k = (t < len) && (v != blank) &&
                           (prev == blank || v != prev);
            vals[j] = v;
            if (k) { keep_mask |= (1u << j); ++cnt; }
            prev = v;
        }
    } else {
        int prev = (t0 == 0) ? -1 : ((t0 - 1 < seq_len) ? row[t0 - 1] : -1);
        for (int j = 0; j < per && j < MAXPER; ++j) {
            const int t = t0 + j;
            if (t >= seq_len) break;
            const int v = row[t];
            const bool k = (t < len) && (v != blank) &&
                           (prev == blank || v != prev);
            vals[j] = v;
            if (k) { keep_mask |= (1u << j); ++cnt; }
            prev = v;
        }
    }

    // Block-wide exclusive prefix sum of cnt (thread order).
    __shared__ int warp_sums[8];
    const int lane = tid & 63;
    const int wid = tid >> 6;
    int incl = cnt;
#pragma unroll
    for (int off = 1; off < 64; off <<= 1) {
        int n = __shfl_up(incl, off, 64);
        if (lane >= off) incl += n;
    }
    if (lane == 63) warp_sums[wid] = incl;
    __syncthreads();

    int wbase = 0;
    for (int w = 0; w < wid; ++w) wbase += warp_sums[w];
    int pos = wbase + incl - cnt;  // exclusive prefix for this thread

    for (int j = 0; j < per && j < MAXPER; ++j) {
        if (keep_mask & (1u << j)) out[pos++] = vals[j];
    }

    if (tid == 0) {
        int total = 0;
        const int nwaves = nthr >> 6;
        for (int w = 0; w < nwaves; ++w) total += warp_sums[w];
        out_lengths[b] = total;
    }
}

extern "C" void kernel_launch(void* const* d_in, const int* in_sizes, int n_in,
                              void* d_out, int out_size, void* d_ws, size_t ws_size,
                              hipStream_t stream) {
    const float* x = (const float*)d_in[0];
    const int* lengths = (const int*)d_in[1];
    const int* blank_ptr = (const int*)d_in[2];

    const int batch = in_sizes[1];
    const int seq_len = (out_size - batch) / batch;      // tokens is (batch, seq_len)
    const int vocab = in_sizes[0] / (seq_len * batch);

    int* tokens = (int*)d_out;                                  // (batch, seq_len)
    int* out_lengths = (int*)d_out + (size_t)batch * seq_len;   // (batch,)
    int* ml = (int*)d_ws;                                       // (batch, seq_len)

    // Kernel 1: 8 tasks per wave (8 lanes each), 4 waves per 256-thread block.
    // Grid sized for the worst case (all rows active); surplus waves retire
    // after the prologue.
    const int nrows = seq_len * batch;
    const int ntasks = (nrows + 7) / 8;
    const int waves_per_block = 4;
    const int blocks1 = (ntasks + waves_per_block - 1) / waves_per_block;
    if (batch <= 64) {
        ctc_argmax_dense<<<blocks1, waves_per_block * 64, 0, stream>>>(
            x, ml, lengths, tokens, seq_len, batch, vocab);
    } else {
        ctc_argmax_kernel<<<blocks1, waves_per_block * 64, 0, stream>>>(
            x, ml, lengths, tokens, seq_len, batch, vocab);
    }

    // Kernel 2: one block per batch element, 512 threads.
    ctc_compact_kernel<<<batch, 512, 0, stream>>>(
        ml, lengths, blank_ptr, tokens, out_lengths, seq_len, batch);
}